// Round 8
// baseline (197.061 us; speedup 1.0000x reference)
//
#include <hip/hip_runtime.h>

#define L 21
#define NVOX 4096
#define ITERS 5
#define NU 210      // monomials of degree <= 4 in 6 vars
#define UPAD 224    // padded rows (210..223 are zero)
#define VPB 16      // voxels per block (P3)
#define NSPLIT 16   // u-splits in P3
#define USPL 14     // u per split (16*14 = 224)
#define NG1 420     // g1 blocks: 210 u x 2 i-halves

// ---------------------------------------------------------------------------
// Phase AB (67 blocks): Phi + nsp + q0(softmax of logits) + W-folds + cu
// table + zero both A2 buffers.
// ---------------------------------------------------------------------------
__global__ __launch_bounds__(256) void phase_ab(
    const float* __restrict__ img, const float* __restrict__ logits,
    const float* __restrict__ Wsp, const float* __restrict__ Wbi,
    const float* __restrict__ Wc,
    float* __restrict__ Phi, float* __restrict__ nsp, float* __restrict__ q,
    float* __restrict__ cu, float* __restrict__ W1, float* __restrict__ W2,
    float* __restrict__ A2)
{
    const int tid = threadIdx.x;
    const int bid = blockIdx.x;
    if (bid < 64) {
        int lane = tid & 63, w = tid >> 6;
        int i = bid * 64 + lane;
        int z = i >> 8, yy = (i >> 4) & 15, xx = i & 15;
        const float ia = 1.0f / 67.0f, ib = 1.0f / 3.0f;
        float f[6];
        f[0] = (float)z * ia; f[1] = (float)yy * ia; f[2] = (float)xx * ia;
        f[3] = img[i] * ib; f[4] = img[NVOX + i] * ib; f[5] = img[2 * NVOX + i] * ib;
        float p[6][5];
#pragma unroll
        for (int c = 0; c < 6; c++) {
            p[c][0] = 1.f;
#pragma unroll
            for (int k = 1; k < 5; k++) p[c][k] = p[c][k - 1] * f[c];
        }
        float hsv = 0.5f * (f[0]*f[0] + f[1]*f[1] + f[2]*f[2] +
                            f[3]*f[3] + f[4]*f[4] + f[5]*f[5]);
        float e0 = __expf(-hsv);
        int ulo = w * 56, uhi = ulo + 56;
        int u = 0;
        for (int a0 = 0; a0 <= 4; a0++)
        for (int a1 = 0; a1 <= 4 - a0; a1++)
        for (int a2 = 0; a2 <= 4 - a0 - a1; a2++)
        for (int a3 = 0; a3 <= 4 - a0 - a1 - a2; a3++)
        for (int a4 = 0; a4 <= 4 - a0 - a1 - a2 - a3; a4++)
        for (int a5 = 0; a5 <= 4 - a0 - a1 - a2 - a3 - a4; a5++) {
            if (u >= ulo && u < uhi)
                Phi[(size_t)u * NVOX + i] =
                    e0 * p[0][a0] * p[1][a1] * p[2][a2] * p[3][a3] * p[4][a4] * p[5][a5];
            u++;
        }
        if (w == 3)
            for (int uz = NU; uz < UPAD; uz++) Phi[(size_t)uz * NVOX + i] = 0.f;
        if (w == 0) {
            float hz = 0.f, hy = 0.f, hx = 0.f;
            for (int t = 0; t < 16; t++) {
                float dz = (float)(z - t), dy = (float)(yy - t), dx = (float)(xx - t);
                hz += __expf(-0.5f * dz * dz);
                hy += __expf(-0.5f * dy * dy);
                hx += __expf(-0.5f * dx * dx);
            }
            nsp[i] = hz * hy * hx;
        }
        if (w == 1) {   // softmax of logits -> q (iteration 0)
            float vals[L]; float mx = -1e30f;
#pragma unroll
            for (int l = 0; l < L; l++) { vals[l] = logits[l * NVOX + i]; mx = fmaxf(mx, vals[l]); }
            float sum = 0.f;
#pragma unroll
            for (int l = 0; l < L; l++) { vals[l] = __expf(vals[l] - mx); sum += vals[l]; }
            float inv = 1.f / sum;
#pragma unroll
            for (int l = 0; l < L; l++) q[l * NVOX + i] = vals[l] * inv;
        }
    } else if (bid == 64) {
        for (int e = tid; e < L * L; e += 256) {
            int r = e / L, c = e % L;
            float s1 = 0.f, s2 = 0.f;
            for (int k = 0; k < L; k++) {
                float wc = Wc[r * L + k];
                s1 = fmaf(wc, Wsp[k * L + c], s1);
                s2 = fmaf(wc, Wbi[k * L + c], s2);
            }
            W1[e] = s1; W2[e] = s2;
        }
    } else if (bid == 65) {
        const float invf[5] = {1.f, 1.f, 0.5f, 1.f / 6.f, 1.f / 24.f};
        float mine = 0.f;   // stays 0 for tid >= NU
        int v = 0;
        for (int a0 = 0; a0 <= 4; a0++)
        for (int a1 = 0; a1 <= 4 - a0; a1++)
        for (int a2 = 0; a2 <= 4 - a0 - a1; a2++)
        for (int a3 = 0; a3 <= 4 - a0 - a1 - a2; a3++)
        for (int a4 = 0; a4 <= 4 - a0 - a1 - a2 - a3; a4++)
        for (int a5 = 0; a5 <= 4 - a0 - a1 - a2 - a3 - a4; a5++) {
            if (v == tid)
                mine = invf[a0] * invf[a1] * invf[a2] * invf[a3] * invf[a4] * invf[a5];
            v++;
        }
        cu[tid] = mine;
    } else {
        // zero BOTH A2 double-buffers (g1 accumulates atomically)
        for (int e = tid; e < 2 * L * UPAD; e += 256) A2[e] = 0.f;
    }
}

// ---------------------------------------------------------------------------
// Phase P2: blocks 0..419 g1 (u = bid>>1, i-half = bid&1; wave = 512-i chunk;
// float4 loads; butterfly reduce; W2/cu fold; atomicAdd into A2cur).
// Blocks 420..440 spatial (exact separable 16-tap gaussian).
// Blocks 441..465 bnorm (it0 only).
// ---------------------------------------------------------------------------
__global__ __launch_bounds__(256) void phase_p2(
    const float* __restrict__ Phi, const float* __restrict__ q,
    const float* __restrict__ cu, const float* __restrict__ W2,
    float* __restrict__ A2cur, float* __restrict__ spv,
    float* __restrict__ bnorm, int it0)
{
    __shared__ float buf[NVOX];
    __shared__ float tmp[NVOX];
    __shared__ float g[16];
    const int tid = threadIdx.x;
    const int bid = blockIdx.x;
    if (bid < NG1) {
        int u = bid >> 1;
        int lane = tid & 63, w = tid >> 6;
        int i0 = (bid & 1) * 2048 + w * 512;
        const float4* ph = (const float4*)(Phi + (size_t)u * NVOX + i0);
        float acc[L];
#pragma unroll
        for (int m = 0; m < L; m++) acc[m] = 0.f;
#pragma unroll
        for (int rep = 0; rep < 2; rep++) {
            int ii = lane + rep * 64;
            float4 p = ph[ii];
#pragma unroll
            for (int m = 0; m < L; m++) {
                float4 qv = ((const float4*)(q + m * NVOX + i0))[ii];
                float d = fmaf(qv.x, p.x, fmaf(qv.y, p.y,
                          fmaf(qv.z, p.z, qv.w * p.w)));
                acc[m] += d;
            }
        }
#pragma unroll
        for (int off = 32; off >= 1; off >>= 1)
#pragma unroll
            for (int m = 0; m < L; m++)
                acc[m] += __shfl_xor(acc[m], off);
        if (lane < L) {
            float dot = 0.f;
#pragma unroll
            for (int m = 0; m < L; m++)
                dot = fmaf(W2[lane * L + m], acc[m], dot);
            atomicAdd(&A2cur[lane * UPAD + u], cu[u] * dot);
        }
    } else if (bid < NG1 + L) {
        int l = bid - NG1;
        if (tid < 16) g[tid] = __expf(-0.5f * (float)(tid * tid));
        for (int k = 0; k < 16; k++)
            buf[tid + 256 * k] = q[l * NVOX + tid + 256 * k];
        __syncthreads();
        for (int k = 0; k < 16; k++) {
            int idx = tid + 256 * k;
            int x = idx & 15, base = idx & ~15;
            float ssum = 0.f;
#pragma unroll
            for (int t = 0; t < 16; t++) {
                int d = x - t; d = d < 0 ? -d : d;
                ssum += g[d] * buf[base + t];
            }
            tmp[idx] = ssum;
        }
        __syncthreads();
        for (int k = 0; k < 16; k++) {
            int idx = tid + 256 * k;
            int y = (idx >> 4) & 15, base = idx & ~(15 << 4);
            float ssum = 0.f;
#pragma unroll
            for (int t = 0; t < 16; t++) {
                int d = y - t; d = d < 0 ? -d : d;
                ssum += g[d] * tmp[base + (t << 4)];
            }
            buf[idx] = ssum;
        }
        __syncthreads();
        for (int k = 0; k < 16; k++) {
            int idx = tid + 256 * k;
            int z = idx >> 8, base = idx & 255;
            float ssum = 0.f;
#pragma unroll
            for (int t = 0; t < 16; t++) {
                int d = z - t; d = d < 0 ? -d : d;
                ssum += g[d] * buf[base + (t << 8)];
            }
            spv[l * NVOX + idx] = ssum;
        }
    } else if (it0) {
        int wg = (bid - (NG1 + L)) * 4 + (tid >> 6);   // 0..99
        int lane = tid & 63;
        for (int u = wg; u < UPAD; u += 25 * 4) {
            const float* row = Phi + (size_t)u * NVOX;
            float ssum = 0.f;
            for (int ii = lane; ii < NVOX; ii += 64) ssum += row[ii];
#pragma unroll
            for (int off = 32; off >= 1; off >>= 1) ssum += __shfl_xor(ssum, off);
            if (lane == 0) bnorm[u] = cu[u] * ssum;
        }
    }
}

// ---------------------------------------------------------------------------
// Phase P3: g2 + combine + softmax-for-next-iter.  256 blocks x 16 voxels.
// Reads A2cur (atomically accumulated by P2) + bnorm; zeroes A2next for the
// following iteration (different buffer — safe to overlap).
// ---------------------------------------------------------------------------
__global__ __launch_bounds__(256) void phase_p3(
    const float* __restrict__ Phi, const float* __restrict__ A2cur,
    float* __restrict__ A2next, const float* __restrict__ bnorm,
    const float* __restrict__ spv, const float* __restrict__ nsp,
    const float* __restrict__ W1, const float* __restrict__ logits,
    float* __restrict__ q, float* __restrict__ out, int last)
{
    __shared__ float sA[L * UPAD];
    __shared__ float sN[UPAD];
    __shared__ float red[22][NSPLIT][VPB];
    __shared__ float sw1[L * L];
    __shared__ float sspn[VPB][22];
    __shared__ float scur[VPB][22];
    const int tid = threadIdx.x;
    const int bid = blockIdx.x;
    const int v = tid & (VPB - 1);
    const int s = tid >> 4;
    const int i16 = bid * VPB + v;

    {   // zero next iteration's A2 buffer (first 19 blocks cover it)
        int e = bid * 256 + tid;
        if (e < L * UPAD) A2next[e] = 0.f;
    }
    for (int e = tid; e < L * UPAD; e += 256) sA[e] = A2cur[e];
    for (int e = tid; e < UPAD; e += 256) sN[e] = bnorm[e];
    for (int e = tid; e < L * L; e += 256) sw1[e] = W1[e];
    {
        float rsp = 1.f / nsp[i16];
        for (int m = s; m < L; m += NSPLIT)
            sspn[v][m] = spv[m * NVOX + i16] * rsp;
    }
    __syncthreads();
    float acc[L], accN = 0.f;
#pragma unroll
    for (int m = 0; m < L; m++) acc[m] = 0.f;
    int u0 = s * USPL;
    for (int uu = 0; uu < USPL; uu++) {
        float p = Phi[(size_t)(u0 + uu) * NVOX + i16];
#pragma unroll
        for (int m = 0; m < L; m++)
            acc[m] = fmaf(sA[m * UPAD + u0 + uu], p, acc[m]);
        accN = fmaf(sN[u0 + uu], p, accN);
    }
#pragma unroll
    for (int m = 0; m < L; m++) red[m][s][v] = acc[m];
    red[21][s][v] = accN;
    __syncthreads();
    float b21 = 0.f;
#pragma unroll
    for (int ss = 0; ss < NSPLIT; ss++) b21 += red[21][ss][v];
    float rbi = 1.f / b21;
    for (int l = s; l < L; l += NSPLIT) {
        float bl = 0.f;
#pragma unroll
        for (int ss = 0; ss < NSPLIT; ss++) bl += red[l][ss][v];
        float r = bl * rbi;
#pragma unroll
        for (int m = 0; m < L; m++)
            r = fmaf(sw1[l * L + m], sspn[v][m], r);
        r += logits[l * NVOX + i16];
        scur[v][l] = r;
        if (last) out[l * NVOX + i16] = r;
    }
    __syncthreads();
    if (!last && tid < VPB) {
        int i = bid * VPB + tid;
        float vals[L]; float mx = -1e30f;
#pragma unroll
        for (int l = 0; l < L; l++) { vals[l] = scur[tid][l]; mx = fmaxf(mx, vals[l]); }
        float sum = 0.f;
#pragma unroll
        for (int l = 0; l < L; l++) { vals[l] = __expf(vals[l] - mx); sum += vals[l]; }
        float inv = 1.f / sum;
#pragma unroll
        for (int l = 0; l < L; l++) q[l * NVOX + i] = vals[l] * inv;
    }
}

extern "C" void kernel_launch(void* const* d_in, const int* in_sizes, int n_in,
                              void* d_out, int out_size, void* d_ws, size_t ws_size,
                              hipStream_t stream) {
    const float* image  = (const float*)d_in[0];
    const float* logits = (const float*)d_in[1];
    const float* Wsp    = (const float*)d_in[2];
    const float* Wbi    = (const float*)d_in[3];
    const float* Wc     = (const float*)d_in[4];
    float* out = (float*)d_out;

    char* ws = (char*)d_ws;
    float* Phi   = (float*)ws; ws += (size_t)UPAD * NVOX * sizeof(float);    // 3.67 MB
    float* nsp   = (float*)ws; ws += (size_t)NVOX * sizeof(float);
    float* q     = (float*)ws; ws += (size_t)L * NVOX * sizeof(float);
    float* spv   = (float*)ws; ws += (size_t)L * NVOX * sizeof(float);
    float* A2    = (float*)ws; ws += (size_t)2 * L * UPAD * sizeof(float);   // double buffer
    float* bnorm = (float*)ws; ws += (size_t)UPAD * sizeof(float);
    float* cu    = (float*)ws; ws += (size_t)256 * sizeof(float);
    float* W1    = (float*)ws; ws += (size_t)L * L * sizeof(float);
    float* W2    = (float*)ws; ws += (size_t)L * L * sizeof(float);

    phase_ab<<<67, 256, 0, stream>>>(image, logits, Wsp, Wbi, Wc,
                                     Phi, nsp, q, cu, W1, W2, A2);
    for (int it = 0; it < ITERS; it++) {
        float* A2cur  = A2 + (it & 1) * L * UPAD;
        float* A2next = A2 + ((it + 1) & 1) * L * UPAD;
        int nb2 = (it == 0) ? 466 : (NG1 + L);
        phase_p2<<<nb2, 256, 0, stream>>>(Phi, q, cu, W2, A2cur, spv, bnorm,
                                          it == 0 ? 1 : 0);
        phase_p3<<<256, 256, 0, stream>>>(Phi, A2cur, A2next, bnorm, spv, nsp,
                                          W1, logits, q, out,
                                          it == ITERS - 1 ? 1 : 0);
    }
}

// Round 9
// 160.846 us; speedup vs baseline: 1.2252x; 1.2252x over previous
//
#include <hip/hip_runtime.h>

#define L 21
#define NVOX 4096
#define ITERS 5
#define NU 210      // monomials of degree <= 4 in 6 vars
#define UPAD 224    // padded rows (210..223 are zero)
#define VPB 16      // voxels per block (P3)
#define NSPLIT 16   // u-splits in P3
#define USPL 14     // u per split (16*14 = 224)

// ---------------------------------------------------------------------------
// Phase AB (67 blocks x 256): Phi + nsp + q0(softmax of logits) + W-folds +
// cu table + zero both A2 buffers (22 rows each; row 21 = normalizer).
// ---------------------------------------------------------------------------
__global__ __launch_bounds__(256) void phase_ab(
    const float* __restrict__ img, const float* __restrict__ logits,
    const float* __restrict__ Wsp, const float* __restrict__ Wbi,
    const float* __restrict__ Wc,
    float* __restrict__ Phi, float* __restrict__ nsp, float* __restrict__ q,
    float* __restrict__ cu, float* __restrict__ W1, float* __restrict__ W2,
    float* __restrict__ A2)
{
    const int tid = threadIdx.x;
    const int bid = blockIdx.x;
    if (bid < 64) {
        int lane = tid & 63, w = tid >> 6;
        int i = bid * 64 + lane;
        int z = i >> 8, yy = (i >> 4) & 15, xx = i & 15;
        const float ia = 1.0f / 67.0f, ib = 1.0f / 3.0f;
        float f[6];
        f[0] = (float)z * ia; f[1] = (float)yy * ia; f[2] = (float)xx * ia;
        f[3] = img[i] * ib; f[4] = img[NVOX + i] * ib; f[5] = img[2 * NVOX + i] * ib;
        float p[6][5];
#pragma unroll
        for (int c = 0; c < 6; c++) {
            p[c][0] = 1.f;
#pragma unroll
            for (int k = 1; k < 5; k++) p[c][k] = p[c][k - 1] * f[c];
        }
        float hsv = 0.5f * (f[0]*f[0] + f[1]*f[1] + f[2]*f[2] +
                            f[3]*f[3] + f[4]*f[4] + f[5]*f[5]);
        float e0 = __expf(-hsv);
        int ulo = w * 56, uhi = ulo + 56;
        int u = 0;
        for (int a0 = 0; a0 <= 4; a0++)
        for (int a1 = 0; a1 <= 4 - a0; a1++)
        for (int a2 = 0; a2 <= 4 - a0 - a1; a2++)
        for (int a3 = 0; a3 <= 4 - a0 - a1 - a2; a3++)
        for (int a4 = 0; a4 <= 4 - a0 - a1 - a2 - a3; a4++)
        for (int a5 = 0; a5 <= 4 - a0 - a1 - a2 - a3 - a4; a5++) {
            if (u >= ulo && u < uhi)
                Phi[(size_t)u * NVOX + i] =
                    e0 * p[0][a0] * p[1][a1] * p[2][a2] * p[3][a3] * p[4][a4] * p[5][a5];
            u++;
        }
        if (w == 3)
            for (int uz = NU; uz < UPAD; uz++) Phi[(size_t)uz * NVOX + i] = 0.f;
        if (w == 0) {
            float hz = 0.f, hy = 0.f, hx = 0.f;
            for (int t = 0; t < 16; t++) {
                float dz = (float)(z - t), dy = (float)(yy - t), dx = (float)(xx - t);
                hz += __expf(-0.5f * dz * dz);
                hy += __expf(-0.5f * dy * dy);
                hx += __expf(-0.5f * dx * dx);
            }
            nsp[i] = hz * hy * hx;
        }
        if (w == 1) {   // softmax of logits -> q (iteration 0)
            float vals[L]; float mx = -1e30f;
#pragma unroll
            for (int l = 0; l < L; l++) { vals[l] = logits[l * NVOX + i]; mx = fmaxf(mx, vals[l]); }
            float sum = 0.f;
#pragma unroll
            for (int l = 0; l < L; l++) { vals[l] = __expf(vals[l] - mx); sum += vals[l]; }
            float inv = 1.f / sum;
#pragma unroll
            for (int l = 0; l < L; l++) q[l * NVOX + i] = vals[l] * inv;
        }
    } else if (bid == 64) {
        for (int e = tid; e < L * L; e += 256) {
            int r = e / L, c = e % L;
            float s1 = 0.f, s2 = 0.f;
            for (int k = 0; k < L; k++) {
                float wc = Wc[r * L + k];
                s1 = fmaf(wc, Wsp[k * L + c], s1);
                s2 = fmaf(wc, Wbi[k * L + c], s2);
            }
            W1[e] = s1; W2[e] = s2;
        }
    } else if (bid == 65) {
        const float invf[5] = {1.f, 1.f, 0.5f, 1.f / 6.f, 1.f / 24.f};
        float mine = 0.f;   // stays 0 for tid >= NU
        int v = 0;
        for (int a0 = 0; a0 <= 4; a0++)
        for (int a1 = 0; a1 <= 4 - a0; a1++)
        for (int a2 = 0; a2 <= 4 - a0 - a1; a2++)
        for (int a3 = 0; a3 <= 4 - a0 - a1 - a2; a3++)
        for (int a4 = 0; a4 <= 4 - a0 - a1 - a2 - a3; a4++)
        for (int a5 = 0; a5 <= 4 - a0 - a1 - a2 - a3 - a4; a5++) {
            if (v == tid)
                mine = invf[a0] * invf[a1] * invf[a2] * invf[a3] * invf[a4] * invf[a5];
            v++;
        }
        cu[tid] = mine;
    } else {
        // zero BOTH A2 double-buffers (22 rows each; g1 accumulates atomically)
        for (int e = tid; e < 2 * 22 * UPAD; e += 256) A2[e] = 0.f;
    }
}

// ---------------------------------------------------------------------------
// Phase P2 (231 blocks x 1024):
//  bid<210: g1 for u=bid.  16 waves x 256-voxel chunks; one float4/row/lane;
//           22 accumulators (21 labels + normalizer sum_i Phi[u][i]);
//           butterfly reduce; W2/cu fold; atomicAdd into A2cur rows 0..21.
//  bid 210..230: spatial label bid-210, exact separable 16-tap gaussian,
//           1024 threads / 4 voxels per thread per pass (R3-verified).
// ---------------------------------------------------------------------------
__global__ __launch_bounds__(1024) void phase_p2(
    const float* __restrict__ Phi, const float* __restrict__ q,
    const float* __restrict__ cu, const float* __restrict__ W2,
    float* __restrict__ A2cur, float* __restrict__ spv)
{
    __shared__ float buf[NVOX];
    __shared__ float tmp[NVOX];
    __shared__ float g[16];
    const int tid = threadIdx.x;
    const int bid = blockIdx.x;
    if (bid < NU) {
        int lane = tid & 63, w = tid >> 4 >> 2;   // wave id 0..15
        int i0 = w * 256;
        float4 p = ((const float4*)(Phi + (size_t)bid * NVOX + i0))[lane];
        float acc[22];
        acc[21] = p.x + p.y + p.z + p.w;          // normalizer partial
#pragma unroll
        for (int m = 0; m < L; m++) {
            float4 qv = ((const float4*)(q + m * NVOX + i0))[lane];
            acc[m] = fmaf(qv.x, p.x, fmaf(qv.y, p.y,
                     fmaf(qv.z, p.z, qv.w * p.w)));
        }
#pragma unroll
        for (int off = 32; off >= 1; off >>= 1)
#pragma unroll
            for (int m = 0; m < 22; m++)
                acc[m] += __shfl_xor(acc[m], off);
        if (lane < 22) {
            float val;
            if (lane < L) {
                float dot = 0.f;
#pragma unroll
                for (int m = 0; m < L; m++)
                    dot = fmaf(W2[lane * L + m], acc[m], dot);
                val = cu[bid] * dot;
            } else {
                val = cu[bid] * acc[21];
            }
            atomicAdd(&A2cur[lane * UPAD + bid], val);
        }
    } else {
        int l = bid - NU;
        if (tid < 16) g[tid] = __expf(-0.5f * (float)(tid * tid));
        for (int k = 0; k < 4; k++)
            buf[tid + 1024 * k] = q[l * NVOX + tid + 1024 * k];
        __syncthreads();
        for (int k = 0; k < 4; k++) {
            int idx = tid + 1024 * k;
            int x = idx & 15, base = idx & ~15;
            float ssum = 0.f;
#pragma unroll
            for (int t = 0; t < 16; t++) {
                int d = x - t; d = d < 0 ? -d : d;
                ssum += g[d] * buf[base + t];
            }
            tmp[idx] = ssum;
        }
        __syncthreads();
        for (int k = 0; k < 4; k++) {
            int idx = tid + 1024 * k;
            int y = (idx >> 4) & 15, base = idx & ~(15 << 4);
            float ssum = 0.f;
#pragma unroll
            for (int t = 0; t < 16; t++) {
                int d = y - t; d = d < 0 ? -d : d;
                ssum += g[d] * tmp[base + (t << 4)];
            }
            buf[idx] = ssum;
        }
        __syncthreads();
        for (int k = 0; k < 4; k++) {
            int idx = tid + 1024 * k;
            int z = idx >> 8, base = idx & 255;
            float ssum = 0.f;
#pragma unroll
            for (int t = 0; t < 16; t++) {
                int d = z - t; d = d < 0 ? -d : d;
                ssum += g[d] * buf[base + (t << 8)];
            }
            spv[l * NVOX + idx] = ssum;
        }
    }
}

// ---------------------------------------------------------------------------
// Phase P3: g2 + combine + softmax-for-next-iter.  256 blocks x 16 voxels.
// Reads A2cur rows 0..20 (bilateral) + row 21 (normalizer); zeroes A2next.
// ---------------------------------------------------------------------------
__global__ __launch_bounds__(256) void phase_p3(
    const float* __restrict__ Phi, const float* __restrict__ A2cur,
    float* __restrict__ A2next, const float* __restrict__ spv,
    const float* __restrict__ nsp, const float* __restrict__ W1,
    const float* __restrict__ logits, float* __restrict__ q,
    float* __restrict__ out, int last)
{
    __shared__ float sA[L * UPAD];
    __shared__ float sN[UPAD];
    __shared__ float red[22][NSPLIT][VPB];
    __shared__ float sw1[L * L];
    __shared__ float sspn[VPB][22];
    __shared__ float scur[VPB][22];
    const int tid = threadIdx.x;
    const int bid = blockIdx.x;
    const int v = tid & (VPB - 1);
    const int s = tid >> 4;
    const int i16 = bid * VPB + v;

    {   // zero next iteration's A2 buffer (22 rows; first 20 blocks cover it)
        int e = bid * 256 + tid;
        if (e < 22 * UPAD) A2next[e] = 0.f;
    }
    for (int e = tid; e < L * UPAD; e += 256) sA[e] = A2cur[e];
    for (int e = tid; e < UPAD; e += 256) sN[e] = A2cur[L * UPAD + e];
    for (int e = tid; e < L * L; e += 256) sw1[e] = W1[e];
    {
        float rsp = 1.f / nsp[i16];
        for (int m = s; m < L; m += NSPLIT)
            sspn[v][m] = spv[m * NVOX + i16] * rsp;
    }
    __syncthreads();
    float acc[L], accN = 0.f;
#pragma unroll
    for (int m = 0; m < L; m++) acc[m] = 0.f;
    int u0 = s * USPL;
    for (int uu = 0; uu < USPL; uu++) {
        float p = Phi[(size_t)(u0 + uu) * NVOX + i16];
#pragma unroll
        for (int m = 0; m < L; m++)
            acc[m] = fmaf(sA[m * UPAD + u0 + uu], p, acc[m]);
        accN = fmaf(sN[u0 + uu], p, accN);
    }
#pragma unroll
    for (int m = 0; m < L; m++) red[m][s][v] = acc[m];
    red[21][s][v] = accN;
    __syncthreads();
    float b21 = 0.f;
#pragma unroll
    for (int ss = 0; ss < NSPLIT; ss++) b21 += red[21][ss][v];
    float rbi = 1.f / b21;
    for (int l = s; l < L; l += NSPLIT) {
        float bl = 0.f;
#pragma unroll
        for (int ss = 0; ss < NSPLIT; ss++) bl += red[l][ss][v];
        float r = bl * rbi;
#pragma unroll
        for (int m = 0; m < L; m++)
            r = fmaf(sw1[l * L + m], sspn[v][m], r);
        r += logits[l * NVOX + i16];
        scur[v][l] = r;
        if (last) out[l * NVOX + i16] = r;
    }
    __syncthreads();
    if (!last && tid < VPB) {
        int i = bid * VPB + tid;
        float vals[L]; float mx = -1e30f;
#pragma unroll
        for (int l = 0; l < L; l++) { vals[l] = scur[tid][l]; mx = fmaxf(mx, vals[l]); }
        float sum = 0.f;
#pragma unroll
        for (int l = 0; l < L; l++) { vals[l] = __expf(vals[l] - mx); sum += vals[l]; }
        float inv = 1.f / sum;
#pragma unroll
        for (int l = 0; l < L; l++) q[l * NVOX + i] = vals[l] * inv;
    }
}

extern "C" void kernel_launch(void* const* d_in, const int* in_sizes, int n_in,
                              void* d_out, int out_size, void* d_ws, size_t ws_size,
                              hipStream_t stream) {
    const float* image  = (const float*)d_in[0];
    const float* logits = (const float*)d_in[1];
    const float* Wsp    = (const float*)d_in[2];
    const float* Wbi    = (const float*)d_in[3];
    const float* Wc     = (const float*)d_in[4];
    float* out = (float*)d_out;

    char* ws = (char*)d_ws;
    float* Phi   = (float*)ws; ws += (size_t)UPAD * NVOX * sizeof(float);    // 3.67 MB
    float* nsp   = (float*)ws; ws += (size_t)NVOX * sizeof(float);
    float* q     = (float*)ws; ws += (size_t)L * NVOX * sizeof(float);
    float* spv   = (float*)ws; ws += (size_t)L * NVOX * sizeof(float);
    float* A2    = (float*)ws; ws += (size_t)2 * 22 * UPAD * sizeof(float);  // double buffer (22 rows)
    float* cu    = (float*)ws; ws += (size_t)256 * sizeof(float);
    float* W1    = (float*)ws; ws += (size_t)L * L * sizeof(float);
    float* W2    = (float*)ws; ws += (size_t)L * L * sizeof(float);

    phase_ab<<<67, 256, 0, stream>>>(image, logits, Wsp, Wbi, Wc,
                                     Phi, nsp, q, cu, W1, W2, A2);
    for (int it = 0; it < ITERS; it++) {
        float* A2cur  = A2 + (it & 1) * 22 * UPAD;
        float* A2next = A2 + ((it + 1) & 1) * 22 * UPAD;
        phase_p2<<<NU + L, 1024, 0, stream>>>(Phi, q, cu, W2, A2cur, spv);
        phase_p3<<<256, 256, 0, stream>>>(Phi, A2cur, A2next, spv, nsp,
                                          W1, logits, q, out,
                                          it == ITERS - 1 ? 1 : 0);
    }
}